// Round 1
// baseline (272.419 us; speedup 1.0000x reference)
//
#include <hip/hip_runtime.h>

// DimensionalConsistencyLoss — MI355X (gfx950)
//
// Structure:
//   dcl_main: blocks 0..2047  -> 4 waves/block, 1 wave per signed constraint
//                                 (wave loads a 2KB row as 2x float4/lane,
//                                  shfl-reduces sum|v|, lane0 finishes loss)
//             blocks 2048..2055 -> 2048 threads, 1 neutral constraint/thread
//             per-block LDS reduce -> one atomicAdd(acc) per block
//   dcl_final: out = 0.5 * acc / 10240
//
// acc lives in d_ws[0], zeroed each call with hipMemsetAsync (capture-safe).

#define DCL_DIM   512
#define DCL_NPOS  4096
#define DCL_NNEG  4096
#define DCL_NNEU  2048
#define DCL_NSIGNED (DCL_NPOS + DCL_NNEG)          // 8192
#define DCL_NCON  (DCL_NPOS + DCL_NNEG + DCL_NNEU) // 10240
#define DCL_SIGNED_BLOCKS (DCL_NSIGNED / 4)        // 2048 (4 waves/block)
#define DCL_NEU_BLOCKS    (DCL_NNEU / 256)         // 8
#define DCL_GRID  (DCL_SIGNED_BLOCKS + DCL_NEU_BLOCKS)

__global__ __launch_bounds__(256) void dcl_main(
    const float* __restrict__ emb,
    const int*   __restrict__ pos_ids, const int* __restrict__ pos_dims,
    const int*   __restrict__ neg_ids, const int* __restrict__ neg_dims,
    const int*   __restrict__ neu_ids, const int* __restrict__ neu_dims,
    float* __restrict__ acc)
{
    const int lane = threadIdx.x & 63;
    const int wv   = threadIdx.x >> 6;   // wave id within block, 0..3

    float contrib = 0.0f;

    if (blockIdx.x < DCL_SIGNED_BLOCKS) {
        // ---- signed constraint: one wave per constraint ----
        const int c = blockIdx.x * 4 + wv;        // 0..8191
        const bool is_pos = (c < DCL_NPOS);
        int id, dim;
        if (is_pos) { id = pos_ids[c];            dim = pos_dims[c]; }
        else        { id = neg_ids[c - DCL_NPOS]; dim = neg_dims[c - DCL_NPOS]; }

        const float*  row = emb + (size_t)id * DCL_DIM;
        const float4* r4  = (const float4*)row;   // 128 float4s per row

        const float4 a = r4[lane];        // dims 4*lane   .. 4*lane+3
        const float4 b = r4[lane + 64];   // dims 256+4*lane ..

        float s = fabsf(a.x) + fabsf(a.y) + fabsf(a.z) + fabsf(a.w)
                + fabsf(b.x) + fabsf(b.y) + fabsf(b.z) + fabsf(b.w);

        #pragma unroll
        for (int o = 32; o >= 1; o >>= 1)
            s += __shfl_down(s, o, 64);   // lane 0 holds sum|row|

        if (lane == 0) {
            const float t  = row[dim];    // L1 hit: row just fetched
            const float at = fabsf(t);
            float sign_loss;
            if (is_pos) sign_loss = (t <= 0.0f) ? (at + 0.1f) : (-0.1f * t);
            else        sign_loss = (t >= 0.0f) ? (at + 0.1f) : (-0.1f * at);
            const float sparsity = 0.1f * (s - at) * (1.0f / 511.0f);
            contrib = sign_loss + sparsity;
        }
    } else {
        // ---- neutral constraints: one thread per constraint ----
        const int idx = (blockIdx.x - DCL_SIGNED_BLOCKS) * 256 + threadIdx.x; // 0..2047
        const int id  = neu_ids[idx];
        const int dim = neu_dims[idx];
        const float v = emb[(size_t)id * DCL_DIM + dim];
        contrib = 2.0f * fabsf(v);
    }

    // ---- block reduce: wave shfl -> LDS -> single atomic ----
    #pragma unroll
    for (int o = 32; o >= 1; o >>= 1)
        contrib += __shfl_down(contrib, o, 64);

    __shared__ float sm[4];
    if (lane == 0) sm[wv] = contrib;
    __syncthreads();
    if (threadIdx.x == 0)
        atomicAdd(acc, sm[0] + sm[1] + sm[2] + sm[3]);
}

__global__ void dcl_final(const float* __restrict__ acc, float* __restrict__ out)
{
    if (threadIdx.x == 0)
        out[0] = 0.5f * acc[0] * (1.0f / (float)DCL_NCON);
}

extern "C" void kernel_launch(void* const* d_in, const int* in_sizes, int n_in,
                              void* d_out, int out_size, void* d_ws, size_t ws_size,
                              hipStream_t stream)
{
    const float* emb      = (const float*)d_in[0];
    const int*   pos_ids  = (const int*)d_in[1];
    const int*   pos_dims = (const int*)d_in[2];
    const int*   neg_ids  = (const int*)d_in[3];
    const int*   neg_dims = (const int*)d_in[4];
    const int*   neu_ids  = (const int*)d_in[5];
    const int*   neu_dims = (const int*)d_in[6];

    float* acc = (float*)d_ws;               // ws is re-poisoned 0xAA each call
    hipMemsetAsync(acc, 0, sizeof(float), stream);

    dcl_main<<<DCL_GRID, 256, 0, stream>>>(emb, pos_ids, pos_dims,
                                           neg_ids, neg_dims,
                                           neu_ids, neu_dims, acc);
    dcl_final<<<1, 64, 0, stream>>>(acc, (float*)d_out);
}

// Round 2
// 250.213 us; speedup vs baseline: 1.0887x; 1.0887x over previous
//
#include <hip/hip_runtime.h>

// DimensionalConsistencyLoss — MI355X (gfx950)
//
// Round 2: no atomics, no memset dispatch.
//   dcl_main:  blocks 0..2047 -> 4 waves/block, 1 signed constraint per wave.
//              Wave reads the 2KB row as 2x float4/lane (coalesced),
//              shfl-reduces sum|v|, gets t via component-select + shfl
//              (no second memory access), lane0 STORES wave partial to ws.
//              blocks 2048..2055 -> 1 neutral gather/thread, wave-reduced,
//              lane0 stores wave partial.
//   dcl_reduce: 1 block, 256 threads, sums 8224 partials, scales, writes out.
//
// ws layout: float partials[8224] — fully overwritten every call, so the
// harness's 0xAA poison is harmless and no pre-zero is needed.

#define DCL_DIM   512
#define DCL_NPOS  4096
#define DCL_NNEG  4096
#define DCL_NNEU  2048
#define DCL_NCON  (DCL_NPOS + DCL_NNEG + DCL_NNEU) // 10240
#define DCL_SIGNED_BLOCKS ((DCL_NPOS + DCL_NNEG) / 4)  // 2048
#define DCL_NEU_BLOCKS    (DCL_NNEU / 256)             // 8
#define DCL_GRID  (DCL_SIGNED_BLOCKS + DCL_NEU_BLOCKS) // 2056
#define DCL_NPART (DCL_GRID * 4)                       // 8224 wave partials

__global__ __launch_bounds__(256) void dcl_main(
    const float* __restrict__ emb,
    const int*   __restrict__ pos_ids, const int* __restrict__ pos_dims,
    const int*   __restrict__ neg_ids, const int* __restrict__ neg_dims,
    const int*   __restrict__ neu_ids, const int* __restrict__ neu_dims,
    float* __restrict__ partials)
{
    const int lane = threadIdx.x & 63;
    const int wv   = threadIdx.x >> 6;   // wave id within block, 0..3

    float contrib;

    if (blockIdx.x < DCL_SIGNED_BLOCKS) {
        // ---- signed constraint: one wave per constraint ----
        const int c = blockIdx.x * 4 + wv;        // 0..8191
        const bool is_pos = (c < DCL_NPOS);
        int id, dim;
        if (is_pos) { id = pos_ids[c];            dim = pos_dims[c]; }
        else        { id = neg_ids[c - DCL_NPOS]; dim = neg_dims[c - DCL_NPOS]; }

        const float4* r4 = (const float4*)(emb + (size_t)id * DCL_DIM);

        const float4 a = r4[lane];        // dims 4*lane .. 4*lane+3
        const float4 b = r4[lane + 64];   // dims 256+4*lane ..

        // t = row[dim] without a second memory access:
        // owning lane is (dim>>2)&63; component is dim&3; half is dim>=256.
        const int comp = dim & 3;
        const float ca = (comp == 0) ? a.x : (comp == 1) ? a.y : (comp == 2) ? a.z : a.w;
        const float cb = (comp == 0) ? b.x : (comp == 1) ? b.y : (comp == 2) ? b.z : b.w;
        const float cand = (dim < 256) ? ca : cb;
        const float t = __shfl(cand, (dim >> 2) & 63, 64);

        float s = fabsf(a.x) + fabsf(a.y) + fabsf(a.z) + fabsf(a.w)
                + fabsf(b.x) + fabsf(b.y) + fabsf(b.z) + fabsf(b.w);
        #pragma unroll
        for (int o = 32; o >= 1; o >>= 1)
            s += __shfl_down(s, o, 64);   // lane 0: sum|row|

        const float at = fabsf(t);
        float sign_loss;
        if (is_pos) sign_loss = (t <= 0.0f) ? (at + 0.1f) : (-0.1f * t);
        else        sign_loss = (t >= 0.0f) ? (at + 0.1f) : (-0.1f * at);
        contrib = sign_loss + 0.1f * (s - at) * (1.0f / 511.0f);
        // only lane 0 has the correct s; lane 0 stores below.
    } else {
        // ---- neutral constraints: one thread per constraint ----
        const int idx = (blockIdx.x - DCL_SIGNED_BLOCKS) * 256 + threadIdx.x;
        const float v = emb[(size_t)neu_ids[idx] * DCL_DIM + neu_dims[idx]];
        float c2 = 2.0f * fabsf(v);
        #pragma unroll
        for (int o = 32; o >= 1; o >>= 1)
            c2 += __shfl_down(c2, o, 64);
        contrib = c2;
    }

    if (lane == 0)
        partials[blockIdx.x * 4 + wv] = contrib;
}

__global__ __launch_bounds__(256) void dcl_reduce(
    const float* __restrict__ partials, float* __restrict__ out)
{
    float s = 0.0f;
    for (int i = threadIdx.x; i < DCL_NPART; i += 256)
        s += partials[i];

    #pragma unroll
    for (int o = 32; o >= 1; o >>= 1)
        s += __shfl_down(s, o, 64);

    __shared__ float sm[4];
    const int lane = threadIdx.x & 63;
    const int wv   = threadIdx.x >> 6;
    if (lane == 0) sm[wv] = s;
    __syncthreads();
    if (threadIdx.x == 0)
        out[0] = (sm[0] + sm[1] + sm[2] + sm[3]) * (0.5f / (float)DCL_NCON);
}

extern "C" void kernel_launch(void* const* d_in, const int* in_sizes, int n_in,
                              void* d_out, int out_size, void* d_ws, size_t ws_size,
                              hipStream_t stream)
{
    const float* emb      = (const float*)d_in[0];
    const int*   pos_ids  = (const int*)d_in[1];
    const int*   pos_dims = (const int*)d_in[2];
    const int*   neg_ids  = (const int*)d_in[3];
    const int*   neg_dims = (const int*)d_in[4];
    const int*   neu_ids  = (const int*)d_in[5];
    const int*   neu_dims = (const int*)d_in[6];

    float* partials = (float*)d_ws;  // 8224 floats, fully overwritten each call

    dcl_main<<<DCL_GRID, 256, 0, stream>>>(emb, pos_ids, pos_dims,
                                           neg_ids, neg_dims,
                                           neu_ids, neu_dims, partials);
    dcl_reduce<<<1, 256, 0, stream>>>(partials, (float*)d_out);
}